// Round 2
// baseline (1102.490 us; speedup 1.0000x reference)
//
#include <hip/hip_runtime.h>
#include <hip/hip_bf16.h>
#include <type_traits>

// Problem constants (fixed by the reference)
#define DM   768
#define NH   12
#define HD   64
#define BATCH 8
#define SEQ  1024
#define NROWS (BATCH * SEQ)   // 8192

typedef short bf16x8 __attribute__((ext_vector_type(8)));
typedef float f32x4 __attribute__((ext_vector_type(4)));

// fp32 -> bf16 bits, round-to-nearest-even (no libcall)
__device__ inline unsigned short f2b(float x) {
    union { float f; unsigned int u; } v; v.f = x;
    unsigned int r = v.u + 0x7FFFu + ((v.u >> 16) & 1u);
    return (unsigned short)(r >> 16);
}
// bf16 bits -> fp32
__device__ inline float b2f(unsigned short u) {
    union { float f; unsigned int x; } v; v.x = ((unsigned int)u) << 16;
    return v.f;
}

// ---------------------------------------------------------------------------
// Kernel 0: per-batch valid lengths from binary masks (int32).
// lens[0..7] = count_nonzero(mask_1[b,:]) ; lens[8..15] = count_nonzero(mask_2[b,:])
// ---------------------------------------------------------------------------
__global__ __launch_bounds__(256) void lens_kernel(const int* __restrict__ m1,
                                                   const int* __restrict__ m2,
                                                   int* __restrict__ lens) {
    __shared__ int red[256];
    const int bid = blockIdx.x;           // 0..15
    const int b = bid & 7;
    const int* m = (bid < 8) ? m1 : m2;
    const int t = threadIdx.x;
    int cnt = 0;
    for (int i = t; i < SEQ; i += 256) cnt += (m[b * SEQ + i] != 0) ? 1 : 0;
    red[t] = cnt;
    __syncthreads();
    for (int off = 128; off > 0; off >>= 1) {
        if (t < off) red[t] += red[t + off];
        __syncthreads();
    }
    if (t == 0) lens[bid] = red[0];
}

// ---------------------------------------------------------------------------
// Kernel 1: MFMA GEMM  C[M,768] = A[M,768] @ W[768,768]  (+bias,+relu,+res)
// A: fp32 (harness inputs) or bf16 bits (intermediates) -> converted to bf16
// in LDS staging. W: always fp32 (harness weights). C: bf16 bits or fp32.
// Block tile 64x64, BK=32, 256 threads = 4 waves; wave w owns C rows 16w..16w+15.
// mfma_f32_16x16x32_bf16 layouts (HW-verified):
//   A: lane holds A[m=lane&15][k=quad*8+j]   (quad = lane>>4, j=0..7)
//   B: lane holds B[k=quad*8+j][n=lane&15]
//   C/D: reg r holds C[row=quad*4+r][col=lane&15]
// LDS k-contiguous rows: As[m][k], Bs[n][k] (W transposed on store). Pad +8.
// ---------------------------------------------------------------------------
template <typename AT, typename CT>
__global__ __launch_bounds__(256) void gemm_k(const AT* __restrict__ A,
                                              const float* __restrict__ W,
                                              CT* __restrict__ C,
                                              const float* __restrict__ bias,
                                              const unsigned short* __restrict__ res,
                                              int relu) {
    __shared__ __align__(16) unsigned short As[64][40];  // [m][k]
    __shared__ __align__(16) unsigned short Bs[64][40];  // [n][k]

    const int t = threadIdx.x;
    const int m0 = blockIdx.x * 64;
    const int n0 = blockIdx.y * 64;
    const int wid = t >> 6;
    const int lane = t & 63;
    const int quad = lane >> 4;
    const int l16 = lane & 15;

    const int am = t >> 2;            // 0..63
    const int ak = (t & 3) * 8;       // 0,8,16,24
    const int bk = t >> 3;            // 0..31
    const int bn = (t & 7) * 8;       // 0,8,...,56

    f32x4 acc[4];
#pragma unroll
    for (int c = 0; c < 4; ++c) acc[c] = (f32x4){0.f, 0.f, 0.f, 0.f};

    for (int k0 = 0; k0 < DM; k0 += 32) {
        // stage A tile (64x32) -> bf16
        if constexpr (std::is_same<AT, float>::value) {
            const float* src = &A[(size_t)(m0 + am) * DM + k0 + ak];
            float4 f0 = *(const float4*)src;
            float4 f1 = *(const float4*)(src + 4);
            unsigned short* d = &As[am][ak];
            d[0] = f2b(f0.x); d[1] = f2b(f0.y); d[2] = f2b(f0.z); d[3] = f2b(f0.w);
            d[4] = f2b(f1.x); d[5] = f2b(f1.y); d[6] = f2b(f1.z); d[7] = f2b(f1.w);
        } else {
            *(uint4*)&As[am][ak] = *(const uint4*)&A[(size_t)(m0 + am) * DM + k0 + ak];
        }
        // stage W tile (32x64) fp32 -> bf16, transposed into Bs[n][k]
        {
            const float* src = &W[(size_t)(k0 + bk) * DM + n0 + bn];
            float4 f0 = *(const float4*)src;
            float4 f1 = *(const float4*)(src + 4);
            Bs[bn + 0][bk] = f2b(f0.x); Bs[bn + 1][bk] = f2b(f0.y);
            Bs[bn + 2][bk] = f2b(f0.z); Bs[bn + 3][bk] = f2b(f0.w);
            Bs[bn + 4][bk] = f2b(f1.x); Bs[bn + 5][bk] = f2b(f1.y);
            Bs[bn + 6][bk] = f2b(f1.z); Bs[bn + 7][bk] = f2b(f1.w);
        }
        __syncthreads();

        bf16x8 av = *(const bf16x8*)&As[16 * wid + l16][quad * 8];
#pragma unroll
        for (int c = 0; c < 4; ++c) {
            bf16x8 bv = *(const bf16x8*)&Bs[16 * c + l16][quad * 8];
            acc[c] = __builtin_amdgcn_mfma_f32_16x16x32_bf16(av, bv, acc[c], 0, 0, 0);
        }
        __syncthreads();
    }

    // epilogue
#pragma unroll
    for (int c = 0; c < 4; ++c) {
        const int gn = n0 + 16 * c + l16;
        float badd = bias ? bias[gn] : 0.0f;
#pragma unroll
        for (int r = 0; r < 4; ++r) {
            const int gm = m0 + 16 * wid + quad * 4 + r;
            float cv = acc[c][r] + badd;
            if (relu) cv = fmaxf(cv, 0.0f);
            if (res) cv += b2f(res[(size_t)gm * DM + gn]);
            if constexpr (std::is_same<CT, float>::value) {
                C[(size_t)gm * DM + gn] = cv;
            } else {
                C[(size_t)gm * DM + gn] = f2b(cv);
            }
        }
    }
}

// ---------------------------------------------------------------------------
// Kernel 2: flash-style attention, fp32 compute from bf16-bit q/k/v buffers.
// One block = 64 Q rows of one (b,h). Online softmax with prefix-length masks.
// Masked scores = -1e6 (NOT skipped): fully-masked query rows must produce the
// reference's uniform softmax over all 1024 keys.
// NOTE: O may alias Q (in-place) — all Q reads complete (LDS staging + barrier)
// before any O write, and each (b,h,qtile) region is private to its block.
// ---------------------------------------------------------------------------
__global__ __launch_bounds__(256) void attn_kernel(const unsigned short* Q,
                                                   const unsigned short* __restrict__ K,
                                                   const unsigned short* __restrict__ V,
                                                   unsigned short* O,
                                                   const int* __restrict__ lens) {
    __shared__ float qt[64][65];
    __shared__ float kvt[64][65];
    __shared__ float st[64][65];
    __shared__ float mrow[64], lrow[64], arow[64];

    const int t = threadIdx.x;
    const int bid = blockIdx.x;                 // 16 * 12 * 8 = 1536
    const int q0 = (bid & 15) * 64;
    const int h = (bid >> 4) % NH;
    const int b = bid / (16 * NH);
    const int vl1 = lens[b];                    // key-axis valid length
    const int vl2 = lens[8 + b];                // query-axis valid length
    const int ty = t >> 4, tx = t & 15;

    for (int e = t; e < 4096; e += 256) {
        int qi = e >> 6, d = e & 63;
        qt[qi][d] = b2f(Q[(size_t)(b * SEQ + q0 + qi) * DM + h * HD + d]);
    }
    if (t < 64) { mrow[t] = -3.0e38f; lrow[t] = 0.0f; }

    float o[4][4];
#pragma unroll
    for (int i = 0; i < 4; ++i)
#pragma unroll
        for (int j = 0; j < 4; ++j) o[i][j] = 0.0f;

    for (int c0 = 0; c0 < SEQ; c0 += 64) {
        __syncthreads();  // prior iteration's kvt readers done (also covers qt staging)
        for (int e = t; e < 4096; e += 256) {
            int ki = e >> 6, d = e & 63;
            kvt[ki][d] = b2f(K[(size_t)(b * SEQ + c0 + ki) * DM + h * HD + d]);
        }
        __syncthreads();

        // scores S = Q Ktile^T (4x4 register blocking)
        float sacc[4][4];
#pragma unroll
        for (int i = 0; i < 4; ++i)
#pragma unroll
            for (int j = 0; j < 4; ++j) sacc[i][j] = 0.0f;
        for (int d = 0; d < 64; ++d) {
            float a[4], bb[4];
#pragma unroll
            for (int i = 0; i < 4; ++i) a[i] = qt[ty + 16 * i][d];
#pragma unroll
            for (int j = 0; j < 4; ++j) bb[j] = kvt[tx + 16 * j][d];
#pragma unroll
            for (int i = 0; i < 4; ++i)
#pragma unroll
                for (int j = 0; j < 4; ++j) sacc[i][j] += a[i] * bb[j];
        }
#pragma unroll
        for (int i = 0; i < 4; ++i)
#pragma unroll
            for (int j = 0; j < 4; ++j) {
                int qi = ty + 16 * i, ki = tx + 16 * j;
                bool ok = ((c0 + ki) < vl1) && ((q0 + qi) < vl2);
                st[qi][ki] = ok ? sacc[i][j] * 0.125f : -1.0e6f;
            }
        __syncthreads();

        // load V into kvt (K no longer needed) while t<64 run softmax on st
        for (int e = t; e < 4096; e += 256) {
            int ki = e >> 6, d = e & 63;
            kvt[ki][d] = b2f(V[(size_t)(b * SEQ + c0 + ki) * DM + h * HD + d]);
        }
        if (t < 64) {
            float m_old = mrow[t];
            float mc = m_old;
            for (int k = 0; k < 64; ++k) mc = fmaxf(mc, st[t][k]);
            float alpha = __expf(m_old - mc);
            float sum = 0.0f;
            for (int k = 0; k < 64; ++k) {
                float p = __expf(st[t][k] - mc);
                st[t][k] = p;
                sum += p;
            }
            lrow[t] = lrow[t] * alpha + sum;
            mrow[t] = mc;
            arow[t] = alpha;
        }
        __syncthreads();

        // O = O*alpha + P @ Vtile
#pragma unroll
        for (int i = 0; i < 4; ++i) {
            float al = arow[ty + 16 * i];
#pragma unroll
            for (int j = 0; j < 4; ++j) o[i][j] *= al;
        }
        for (int k = 0; k < 64; ++k) {
            float a[4], bb[4];
#pragma unroll
            for (int i = 0; i < 4; ++i) a[i] = st[ty + 16 * i][k];
#pragma unroll
            for (int j = 0; j < 4; ++j) bb[j] = kvt[k][tx + 16 * j];
#pragma unroll
            for (int i = 0; i < 4; ++i)
#pragma unroll
                for (int j = 0; j < 4; ++j) o[i][j] += a[i] * bb[j];
        }
    }

#pragma unroll
    for (int i = 0; i < 4; ++i) {
        int qi = ty + 16 * i;
        float inv = 1.0f / lrow[qi];
#pragma unroll
        for (int j = 0; j < 4; ++j) {
            O[(size_t)(b * SEQ + q0 + qi) * DM + h * HD + tx + 16 * j] =
                f2b(o[i][j] * inv);
        }
    }
}

// ---------------------------------------------------------------------------
// Kernel 3: row LayerNorm over D=768, fp32 in/out, IN PLACE on d_out.
// ---------------------------------------------------------------------------
__global__ __launch_bounds__(256) void ln_kernel(float* __restrict__ X,
                                                 const float* __restrict__ g,
                                                 const float* __restrict__ bvec) {
    __shared__ float red[256];
    const int row = blockIdx.x;
    const int t = threadIdx.x;
    float* xr = X + (size_t)row * DM;
    float x0 = xr[t];
    float x1 = xr[t + 256];
    float x2 = xr[t + 512];
    red[t] = x0 + x1 + x2;
    __syncthreads();
    for (int off = 128; off > 0; off >>= 1) {
        if (t < off) red[t] += red[t + off];
        __syncthreads();
    }
    float mu = red[0] * (1.0f / 768.0f);
    __syncthreads();
    float d0 = x0 - mu, d1 = x1 - mu, d2 = x2 - mu;
    red[t] = d0 * d0 + d1 * d1 + d2 * d2;
    __syncthreads();
    for (int off = 128; off > 0; off >>= 1) {
        if (t < off) red[t] += red[t + off];
        __syncthreads();
    }
    float rstd = rsqrtf(red[0] * (1.0f / 768.0f) + 1e-5f);
    xr[t]       = d0 * rstd * g[t]       + bvec[t];
    xr[t + 256] = d1 * rstd * g[t + 256] + bvec[t + 256];
    xr[t + 512] = d2 * rstd * g[t + 512] + bvec[t + 512];
}

// ---------------------------------------------------------------------------
extern "C" void kernel_launch(void* const* d_in, const int* in_sizes, int n_in,
                              void* d_out, int out_size, void* d_ws, size_t ws_size,
                              hipStream_t stream) {
    const float* queries = (const float*)d_in[0];
    const float* keys    = (const float*)d_in[1];
    const float* values  = (const float*)d_in[2];
    const int* mask1 = (const int*)d_in[3];
    const int* mask2 = (const int*)d_in[4];
    const float* Wq  = (const float*)d_in[5];
    const float* Wk  = (const float*)d_in[6];
    const float* Wv  = (const float*)d_in[7];
    const float* Wo  = (const float*)d_in[8];
    const float* d1w = (const float*)d_in[9];
    const float* d1b = (const float*)d_in[10];
    const float* d2w = (const float*)d_in[11];
    const float* d2b = (const float*)d_in[12];
    const float* lng = (const float*)d_in[13];
    const float* lnb = (const float*)d_in[14];

    // workspace: [lens 256B][b0][b1][b2], bf16-bit buffers (12.6 MB each)
    // b0: q -> attn-out (in place) ; b1: k -> mha ; b2: v -> ffn-hidden
    char* ws = (char*)d_ws;
    int* lens = (int*)ws;
    const size_t NB = (size_t)NROWS * DM * sizeof(unsigned short);
    unsigned short* b0 = (unsigned short*)(ws + 256);
    unsigned short* b1 = (unsigned short*)(ws + 256 + NB);
    unsigned short* b2 = (unsigned short*)(ws + 256 + 2 * NB);
    float* xout = (float*)d_out;

    lens_kernel<<<16, 256, 0, stream>>>(mask1, mask2, lens);

    const dim3 gg(NROWS / 64, DM / 64);  // 128 x 12
    gemm_k<float, unsigned short><<<gg, 256, 0, stream>>>(queries, Wq, b0, nullptr, nullptr, 0);
    gemm_k<float, unsigned short><<<gg, 256, 0, stream>>>(keys,    Wk, b1, nullptr, nullptr, 0);
    gemm_k<float, unsigned short><<<gg, 256, 0, stream>>>(values,  Wv, b2, nullptr, nullptr, 0);

    attn_kernel<<<16 * NH * BATCH, 256, 0, stream>>>(b0, b1, b2, b0, lens);  // O in place over Q

    gemm_k<unsigned short, unsigned short><<<gg, 256, 0, stream>>>(b0, Wo,  b1, nullptr, nullptr, 0);  // mha -> b1
    gemm_k<unsigned short, unsigned short><<<gg, 256, 0, stream>>>(b1, d1w, b2, d1b, nullptr, 1);      // ffn_h -> b2
    gemm_k<unsigned short, float><<<gg, 256, 0, stream>>>(b2, d2w, xout, d2b, b1, 0);                  // x -> d_out (fp32)

    ln_kernel<<<NROWS, 256, 0, stream>>>(xout, lng, lnb);  // in place
}

// Round 3
// 569.976 us; speedup vs baseline: 1.9343x; 1.9343x over previous
//
#include <hip/hip_runtime.h>
#include <hip/hip_bf16.h>
#include <type_traits>

// Problem constants (fixed by the reference)
#define DM   768
#define NH   12
#define HD   64
#define BATCH 8
#define SEQ  1024
#define NROWS (BATCH * SEQ)   // 8192

typedef short bf16x8 __attribute__((ext_vector_type(8)));
typedef float f32x4 __attribute__((ext_vector_type(4)));

// fp32 -> bf16 bits, round-to-nearest-even (no libcall)
__device__ inline unsigned short f2b(float x) {
    union { float f; unsigned int u; } v; v.f = x;
    unsigned int r = v.u + 0x7FFFu + ((v.u >> 16) & 1u);
    return (unsigned short)(r >> 16);
}
// bf16 bits -> fp32
__device__ inline float b2f(unsigned short u) {
    union { float f; unsigned int x; } v; v.x = ((unsigned int)u) << 16;
    return v.f;
}

// ---------------------------------------------------------------------------
// Kernel 0: per-batch valid lengths from binary masks (int32).
// ---------------------------------------------------------------------------
__global__ __launch_bounds__(256) void lens_kernel(const int* __restrict__ m1,
                                                   const int* __restrict__ m2,
                                                   int* __restrict__ lens) {
    __shared__ int red[256];
    const int bid = blockIdx.x;           // 0..15
    const int b = bid & 7;
    const int* m = (bid < 8) ? m1 : m2;
    const int t = threadIdx.x;
    int cnt = 0;
    for (int i = t; i < SEQ; i += 256) cnt += (m[b * SEQ + i] != 0) ? 1 : 0;
    red[t] = cnt;
    __syncthreads();
    for (int off = 128; off > 0; off >>= 1) {
        if (t < off) red[t] += red[t + off];
        __syncthreads();
    }
    if (t == 0) lens[bid] = red[0];
}

// ---------------------------------------------------------------------------
// Kernel 1: MFMA GEMM  C[M,768] = A[M,768] @ W[768,768]  (+bias,+relu,+res)
// (unchanged from round 2 — passing)
// ---------------------------------------------------------------------------
template <typename AT, typename CT>
__global__ __launch_bounds__(256) void gemm_k(const AT* __restrict__ A,
                                              const float* __restrict__ W,
                                              CT* __restrict__ C,
                                              const float* __restrict__ bias,
                                              const unsigned short* __restrict__ res,
                                              int relu) {
    __shared__ __align__(16) unsigned short As[64][40];  // [m][k]
    __shared__ __align__(16) unsigned short Bs[64][40];  // [n][k]

    const int t = threadIdx.x;
    const int m0 = blockIdx.x * 64;
    const int n0 = blockIdx.y * 64;
    const int wid = t >> 6;
    const int lane = t & 63;
    const int quad = lane >> 4;
    const int l16 = lane & 15;

    const int am = t >> 2;            // 0..63
    const int ak = (t & 3) * 8;       // 0,8,16,24
    const int bk = t >> 3;            // 0..31
    const int bn = (t & 7) * 8;       // 0,8,...,56

    f32x4 acc[4];
#pragma unroll
    for (int c = 0; c < 4; ++c) acc[c] = (f32x4){0.f, 0.f, 0.f, 0.f};

    for (int k0 = 0; k0 < DM; k0 += 32) {
        if constexpr (std::is_same<AT, float>::value) {
            const float* src = &A[(size_t)(m0 + am) * DM + k0 + ak];
            float4 f0 = *(const float4*)src;
            float4 f1 = *(const float4*)(src + 4);
            unsigned short* d = &As[am][ak];
            d[0] = f2b(f0.x); d[1] = f2b(f0.y); d[2] = f2b(f0.z); d[3] = f2b(f0.w);
            d[4] = f2b(f1.x); d[5] = f2b(f1.y); d[6] = f2b(f1.z); d[7] = f2b(f1.w);
        } else {
            *(uint4*)&As[am][ak] = *(const uint4*)&A[(size_t)(m0 + am) * DM + k0 + ak];
        }
        {
            const float* src = &W[(size_t)(k0 + bk) * DM + n0 + bn];
            float4 f0 = *(const float4*)src;
            float4 f1 = *(const float4*)(src + 4);
            Bs[bn + 0][bk] = f2b(f0.x); Bs[bn + 1][bk] = f2b(f0.y);
            Bs[bn + 2][bk] = f2b(f0.z); Bs[bn + 3][bk] = f2b(f0.w);
            Bs[bn + 4][bk] = f2b(f1.x); Bs[bn + 5][bk] = f2b(f1.y);
            Bs[bn + 6][bk] = f2b(f1.z); Bs[bn + 7][bk] = f2b(f1.w);
        }
        __syncthreads();

        bf16x8 av = *(const bf16x8*)&As[16 * wid + l16][quad * 8];
#pragma unroll
        for (int c = 0; c < 4; ++c) {
            bf16x8 bv = *(const bf16x8*)&Bs[16 * c + l16][quad * 8];
            acc[c] = __builtin_amdgcn_mfma_f32_16x16x32_bf16(av, bv, acc[c], 0, 0, 0);
        }
        __syncthreads();
    }

#pragma unroll
    for (int c = 0; c < 4; ++c) {
        const int gn = n0 + 16 * c + l16;
        float badd = bias ? bias[gn] : 0.0f;
#pragma unroll
        for (int r = 0; r < 4; ++r) {
            const int gm = m0 + 16 * wid + quad * 4 + r;
            float cv = acc[c][r] + badd;
            if (relu) cv = fmaxf(cv, 0.0f);
            if (res) cv += b2f(res[(size_t)gm * DM + gn]);
            if constexpr (std::is_same<CT, float>::value) {
                C[(size_t)gm * DM + gn] = cv;
            } else {
                C[(size_t)gm * DM + gn] = f2b(cv);
            }
        }
    }
}

// ---------------------------------------------------------------------------
// Kernel 2: MFMA flash attention (bf16 in/out, fp32 softmax/accum).
// Block = 64 Q rows of one (b,h), 4 waves; wave w owns Q rows 16w..16w+15.
// Q fragments stay in registers for the whole kernel. Per 64-key tile:
//   S = Q K^T : 4 col-tiles x 2 k-chunks mfma_f32_16x16x32_bf16
//   online softmax fully in registers (shfl_xor over the 16-lane C-layout row
//   groups); masked scores = -1e6 (fully-masked rows -> uniform softmax,
//   matching the reference).
//   P: C-layout -> bf16 -> per-wave-private LDS -> A-layout (no barrier needed)
//   PV: V staged transposed Vt[hd][key]; write pattern (hc=t>>5, kr=t&31)
//       keeps bank = 4j + kr/2 -> <=4-way write conflicts.
// O written in place over Q (regions disjoint per block; Q read only at start).
// ---------------------------------------------------------------------------
__global__ __launch_bounds__(256) void attn_mfma(const unsigned short* Q,
                                                 const unsigned short* __restrict__ K,
                                                 const unsigned short* __restrict__ V,
                                                 unsigned short* O,
                                                 const int* __restrict__ lens) {
    __shared__ __align__(16) unsigned short Ks[64][72];      // [key][hd]
    __shared__ __align__(16) unsigned short Vt[64][72];      // [hd][key]
    __shared__ __align__(16) unsigned short Ps[4][16][72];   // per-wave [qrow][key]

    const int t = threadIdx.x;
    const int bid = blockIdx.x;                 // 16 * 12 * 8 = 1536
    const int q0 = (bid & 15) * 64;
    const int h = (bid >> 4) % NH;
    const int b = bid / (16 * NH);
    const int vl1 = lens[b];                    // key-axis valid length
    const int vl2 = lens[8 + b];                // query-axis valid length
    const int wid = t >> 6;
    const int lane = t & 63;
    const int quad = lane >> 4;
    const int l16 = lane & 15;

    // Q fragments (A-operand): rows q0+16*wid+l16, k = hd
    bf16x8 qa0, qa1;
    {
        const unsigned short* qp =
            &Q[(size_t)(b * SEQ + q0 + 16 * wid + l16) * DM + h * HD + quad * 8];
        qa0 = *(const bf16x8*)qp;
        qa1 = *(const bf16x8*)(qp + 32);
    }

    f32x4 o[4];
#pragma unroll
    for (int ct = 0; ct < 4; ++ct) o[ct] = (f32x4){0.f, 0.f, 0.f, 0.f};
    float m_i[4], l_i[4];
    bool qok[4];
#pragma unroll
    for (int r = 0; r < 4; ++r) {
        m_i[r] = -3.0e38f;
        l_i[r] = 0.0f;
        qok[r] = (q0 + 16 * wid + quad * 4 + r) < vl2;
    }

    // staging assignments
    const int kkr = t >> 3;            // K: key row 0..31
    const int khc = (t & 7) * 8;       // K: hd offset
    const int vkr = t & 31;            // V: key row 0..31
    const int vhc = t >> 5;            // V: hd block 0..7

    for (int c0 = 0; c0 < SEQ; c0 += 64) {
        __syncthreads();  // previous tile's Ks/Vt readers done
        // stage K tile row-major
        {
            const unsigned short* kp = &K[(size_t)(b * SEQ + c0 + kkr) * DM + h * HD + khc];
            *(uint4*)&Ks[kkr][khc] = *(const uint4*)kp;
            *(uint4*)&Ks[kkr + 32][khc] = *(const uint4*)(kp + (size_t)32 * DM);
        }
        // stage V transposed -> Vt[hd][key]
#pragma unroll
        for (int it = 0; it < 2; ++it) {
            union { uint4 u; unsigned short s[8]; } vv;
            vv.u = *(const uint4*)&V[(size_t)(b * SEQ + c0 + vkr + 32 * it) * DM + h * HD + vhc * 8];
#pragma unroll
            for (int j = 0; j < 8; ++j) Vt[vhc * 8 + j][vkr + 32 * it] = vv.s[j];
        }
        __syncthreads();

        // S = Q K^T  (C layout: reg r = row quad*4+r, col = 16ct+l16)
        f32x4 s[4];
#pragma unroll
        for (int ct = 0; ct < 4; ++ct) {
            f32x4 acc = (f32x4){0.f, 0.f, 0.f, 0.f};
            bf16x8 b0v = *(const bf16x8*)&Ks[16 * ct + l16][quad * 8];
            bf16x8 b1v = *(const bf16x8*)&Ks[16 * ct + l16][32 + quad * 8];
            acc = __builtin_amdgcn_mfma_f32_16x16x32_bf16(qa0, b0v, acc, 0, 0, 0);
            acc = __builtin_amdgcn_mfma_f32_16x16x32_bf16(qa1, b1v, acc, 0, 0, 0);
            s[ct] = acc;
        }
        // mask + scale
#pragma unroll
        for (int ct = 0; ct < 4; ++ct) {
            const bool kok = (c0 + 16 * ct + l16) < vl1;
#pragma unroll
            for (int r = 0; r < 4; ++r) {
                s[ct][r] = (kok && qok[r]) ? s[ct][r] * 0.125f : -1.0e6f;
            }
        }
        // row max (across 4 col-tiles, then across the 16 lanes of the row group)
        float mx[4];
#pragma unroll
        for (int r = 0; r < 4; ++r)
            mx[r] = fmaxf(fmaxf(s[0][r], s[1][r]), fmaxf(s[2][r], s[3][r]));
#pragma unroll
        for (int d = 1; d < 16; d <<= 1) {
#pragma unroll
            for (int r = 0; r < 4; ++r) mx[r] = fmaxf(mx[r], __shfl_xor(mx[r], d, 64));
        }
        float alpha[4], sum[4];
#pragma unroll
        for (int r = 0; r < 4; ++r) {
            float mn = fmaxf(m_i[r], mx[r]);
            alpha[r] = __expf(m_i[r] - mn);
            m_i[r] = mn;
            sum[r] = 0.0f;
        }
        // p = exp(s - m)
#pragma unroll
        for (int ct = 0; ct < 4; ++ct) {
#pragma unroll
            for (int r = 0; r < 4; ++r) {
                float p = __expf(s[ct][r] - m_i[r]);
                s[ct][r] = p;
                sum[r] += p;
            }
        }
#pragma unroll
        for (int d = 1; d < 16; d <<= 1) {
#pragma unroll
            for (int r = 0; r < 4; ++r) sum[r] += __shfl_xor(sum[r], d, 64);
        }
#pragma unroll
        for (int r = 0; r < 4; ++r) l_i[r] = l_i[r] * alpha[r] + sum[r];
        // rescale O
#pragma unroll
        for (int ct = 0; ct < 4; ++ct)
#pragma unroll
            for (int r = 0; r < 4; ++r) o[ct][r] *= alpha[r];
        // P -> per-wave LDS (C layout -> A layout round trip)
#pragma unroll
        for (int ct = 0; ct < 4; ++ct)
#pragma unroll
            for (int r = 0; r < 4; ++r)
                Ps[wid][quad * 4 + r][16 * ct + l16] = f2b(s[ct][r]);
        bf16x8 pa0 = *(const bf16x8*)&Ps[wid][l16][quad * 8];
        bf16x8 pa1 = *(const bf16x8*)&Ps[wid][l16][32 + quad * 8];
        // O += P V
#pragma unroll
        for (int ct = 0; ct < 4; ++ct) {
            bf16x8 vb0 = *(const bf16x8*)&Vt[16 * ct + l16][quad * 8];
            bf16x8 vb1 = *(const bf16x8*)&Vt[16 * ct + l16][32 + quad * 8];
            o[ct] = __builtin_amdgcn_mfma_f32_16x16x32_bf16(pa0, vb0, o[ct], 0, 0, 0);
            o[ct] = __builtin_amdgcn_mfma_f32_16x16x32_bf16(pa1, vb1, o[ct], 0, 0, 0);
        }
    }

    // epilogue: O /= l  (l_i replicated across the 16 lanes of each row group)
#pragma unroll
    for (int r = 0; r < 4; ++r) {
        float inv = 1.0f / l_i[r];
        const size_t row = (size_t)(b * SEQ + q0 + 16 * wid + quad * 4 + r);
#pragma unroll
        for (int ct = 0; ct < 4; ++ct) {
            O[row * DM + h * HD + 16 * ct + l16] = f2b(o[ct][r] * inv);
        }
    }
}

// ---------------------------------------------------------------------------
// Kernel 3: row LayerNorm over D=768, fp32 in/out, IN PLACE on d_out.
// ---------------------------------------------------------------------------
__global__ __launch_bounds__(256) void ln_kernel(float* __restrict__ X,
                                                 const float* __restrict__ g,
                                                 const float* __restrict__ bvec) {
    __shared__ float red[256];
    const int row = blockIdx.x;
    const int t = threadIdx.x;
    float* xr = X + (size_t)row * DM;
    float x0 = xr[t];
    float x1 = xr[t + 256];
    float x2 = xr[t + 512];
    red[t] = x0 + x1 + x2;
    __syncthreads();
    for (int off = 128; off > 0; off >>= 1) {
        if (t < off) red[t] += red[t + off];
        __syncthreads();
    }
    float mu = red[0] * (1.0f / 768.0f);
    __syncthreads();
    float d0 = x0 - mu, d1 = x1 - mu, d2 = x2 - mu;
    red[t] = d0 * d0 + d1 * d1 + d2 * d2;
    __syncthreads();
    for (int off = 128; off > 0; off >>= 1) {
        if (t < off) red[t] += red[t + off];
        __syncthreads();
    }
    float rstd = rsqrtf(red[0] * (1.0f / 768.0f) + 1e-5f);
    xr[t]       = d0 * rstd * g[t]       + bvec[t];
    xr[t + 256] = d1 * rstd * g[t + 256] + bvec[t + 256];
    xr[t + 512] = d2 * rstd * g[t + 512] + bvec[t + 512];
}

// ---------------------------------------------------------------------------
extern "C" void kernel_launch(void* const* d_in, const int* in_sizes, int n_in,
                              void* d_out, int out_size, void* d_ws, size_t ws_size,
                              hipStream_t stream) {
    const float* queries = (const float*)d_in[0];
    const float* keys    = (const float*)d_in[1];
    const float* values  = (const float*)d_in[2];
    const int* mask1 = (const int*)d_in[3];
    const int* mask2 = (const int*)d_in[4];
    const float* Wq  = (const float*)d_in[5];
    const float* Wk  = (const float*)d_in[6];
    const float* Wv  = (const float*)d_in[7];
    const float* Wo  = (const float*)d_in[8];
    const float* d1w = (const float*)d_in[9];
    const float* d1b = (const float*)d_in[10];
    const float* d2w = (const float*)d_in[11];
    const float* d2b = (const float*)d_in[12];
    const float* lng = (const float*)d_in[13];
    const float* lnb = (const float*)d_in[14];

    // workspace: [lens 256B][b0][b1][b2], bf16-bit buffers (12.6 MB each)
    char* ws = (char*)d_ws;
    int* lens = (int*)ws;
    const size_t NB = (size_t)NROWS * DM * sizeof(unsigned short);
    unsigned short* b0 = (unsigned short*)(ws + 256);
    unsigned short* b1 = (unsigned short*)(ws + 256 + NB);
    unsigned short* b2 = (unsigned short*)(ws + 256 + 2 * NB);
    float* xout = (float*)d_out;

    lens_kernel<<<16, 256, 0, stream>>>(mask1, mask2, lens);

    const dim3 gg(NROWS / 64, DM / 64);  // 128 x 12
    gemm_k<float, unsigned short><<<gg, 256, 0, stream>>>(queries, Wq, b0, nullptr, nullptr, 0);
    gemm_k<float, unsigned short><<<gg, 256, 0, stream>>>(keys,    Wk, b1, nullptr, nullptr, 0);
    gemm_k<float, unsigned short><<<gg, 256, 0, stream>>>(values,  Wv, b2, nullptr, nullptr, 0);

    attn_mfma<<<16 * NH * BATCH, 256, 0, stream>>>(b0, b1, b2, b0, lens);  // O in place over Q

    gemm_k<unsigned short, unsigned short><<<gg, 256, 0, stream>>>(b0, Wo,  b1, nullptr, nullptr, 0);  // mha -> b1
    gemm_k<unsigned short, unsigned short><<<gg, 256, 0, stream>>>(b1, d1w, b2, d1b, nullptr, 1);      // ffn_h -> b2
    gemm_k<unsigned short, float><<<gg, 256, 0, stream>>>(b2, d2w, xout, d2b, b1, 0);                  // x -> d_out (fp32)

    ln_kernel<<<NROWS, 256, 0, stream>>>(xout, lng, lnb);  // in place
}

// Round 4
// 399.570 us; speedup vs baseline: 2.7592x; 1.4265x over previous
//
#include <hip/hip_runtime.h>
#include <hip/hip_bf16.h>
#include <type_traits>

// Problem constants (fixed by the reference)
#define DM   768
#define NH   12
#define HD   64
#define BATCH 8
#define SEQ  1024
#define NROWS (BATCH * SEQ)   // 8192

typedef short bf16x8 __attribute__((ext_vector_type(8)));
typedef float f32x4 __attribute__((ext_vector_type(4)));

// fp32 -> bf16 bits, round-to-nearest-even (no libcall)
__device__ inline unsigned short f2b(float x) {
    union { float f; unsigned int u; } v; v.f = x;
    unsigned int r = v.u + 0x7FFFu + ((v.u >> 16) & 1u);
    return (unsigned short)(r >> 16);
}
// bf16 bits -> fp32
__device__ inline float b2f(unsigned short u) {
    union { float f; unsigned int x; } v; v.x = ((unsigned int)u) << 16;
    return v.f;
}

// async global->LDS, 16 B per lane; LDS dest = wave-uniform base + lane*16
__device__ inline void gld16(const unsigned short* g, unsigned short* l) {
    __builtin_amdgcn_global_load_lds(
        (const __attribute__((address_space(1))) unsigned int*)g,
        (__attribute__((address_space(3))) unsigned int*)l, 16, 0, 0);
}

// ---------------------------------------------------------------------------
// Kernel 0: per-batch valid lengths from binary masks (int32).
// ---------------------------------------------------------------------------
__global__ __launch_bounds__(256) void lens_kernel(const int* __restrict__ m1,
                                                   const int* __restrict__ m2,
                                                   int* __restrict__ lens) {
    __shared__ int red[256];
    const int bid = blockIdx.x;           // 0..15
    const int b = bid & 7;
    const int* m = (bid < 8) ? m1 : m2;
    const int t = threadIdx.x;
    int cnt = 0;
    for (int i = t; i < SEQ; i += 256) cnt += (m[b * SEQ + i] != 0) ? 1 : 0;
    red[t] = cnt;
    __syncthreads();
    for (int off = 128; off > 0; off >>= 1) {
        if (t < off) red[t] += red[t + off];
        __syncthreads();
    }
    if (t == 0) lens[bid] = red[0];
}

// ---------------------------------------------------------------------------
// Kernel 0b: convert+transpose the 6 weight matrices.
// W[k][n] fp32  ->  Wt[n][k] bf16 bits   (z = which weight)
// ---------------------------------------------------------------------------
__global__ __launch_bounds__(256) void cvt_wt(const float* __restrict__ w0,
                                              const float* __restrict__ w1,
                                              const float* __restrict__ w2,
                                              const float* __restrict__ w3,
                                              const float* __restrict__ w4,
                                              const float* __restrict__ w5,
                                              unsigned short* __restrict__ wt) {
    __shared__ float tile[32][33];
    const int z = blockIdx.z;
    const float* W = (z == 0) ? w0 : (z == 1) ? w1 : (z == 2) ? w2
                   : (z == 3) ? w3 : (z == 4) ? w4 : w5;
    unsigned short* Wt = wt + (size_t)z * DM * DM;
    const int n0 = blockIdx.x * 32;
    const int k0 = blockIdx.y * 32;
    const int tx = threadIdx.x & 31;
    const int ty = threadIdx.x >> 5;  // 0..7
#pragma unroll
    for (int r = 0; r < 4; ++r)
        tile[ty + 8 * r][tx] = W[(size_t)(k0 + ty + 8 * r) * DM + n0 + tx];
    __syncthreads();
#pragma unroll
    for (int r = 0; r < 4; ++r)
        Wt[(size_t)(n0 + ty + 8 * r) * DM + k0 + tx] = f2b(tile[tx][ty + 8 * r]);
}

// ---------------------------------------------------------------------------
// Kernel 1a: grouped QKV GEMM. group g = blockIdx.y/6 selects (A,Wt,C).
// A fp32 (harness input) staged through VGPR f2b; Wt bf16 via global_load_lds.
// Tile 128x128, BK=32, 4 waves; wave w=(wm,wn) computes a 64x64 quadrant as
// 4x4 mfma_f32_16x16x32_bf16 tiles.
// ---------------------------------------------------------------------------
__global__ __launch_bounds__(256) void qkv_gemm(const float* __restrict__ a0,
                                                const float* __restrict__ a1,
                                                const float* __restrict__ a2,
                                                const unsigned short* __restrict__ wt,
                                                unsigned short* __restrict__ c0,
                                                unsigned short* __restrict__ c1,
                                                unsigned short* __restrict__ c2) {
    __shared__ __align__(16) unsigned short As[128][32];
    __shared__ __align__(16) unsigned short Ws[128][32];

    const int t = threadIdx.x;
    const int g = blockIdx.y / 6;
    const int m0 = blockIdx.x * 128;
    const int n0 = (blockIdx.y % 6) * 128;
    const float* A = (g == 0) ? a0 : (g == 1) ? a1 : a2;
    const unsigned short* Wt = wt + (size_t)g * DM * DM;
    unsigned short* C = (g == 0) ? c0 : (g == 1) ? c1 : c2;

    const int w = t >> 6, lane = t & 63;
    const int quad = lane >> 4, l16 = lane & 15;
    const int wm = w & 1, wn = w >> 1;
    // Wt staging (global_load_lds): instr j covers rows 16*(w+4j)
    const int srow = 16 * w + (lane >> 2);
    const int scol = 8 * (lane & 3);
    // A staging (fp32 VGPR convert): thread t covers row t>>1, cols (t&1)*16..+15
    const int ar = t >> 1;
    const int ac = (t & 1) * 16;

    f32x4 acc[4][4];
#pragma unroll
    for (int i = 0; i < 4; ++i)
#pragma unroll
        for (int j = 0; j < 4; ++j) acc[i][j] = (f32x4){0.f, 0.f, 0.f, 0.f};

    for (int k0 = 0; k0 < DM; k0 += 32) {
#pragma unroll
        for (int j = 0; j < 2; ++j)
            gld16(&Wt[(size_t)(n0 + srow + 64 * j) * DM + k0 + scol],
                  &Ws[16 * w + 64 * j][0]);
        {
            const float* src = &A[(size_t)(m0 + ar) * DM + k0 + ac];
            float4 f0 = ((const float4*)src)[0];
            float4 f1 = ((const float4*)src)[1];
            float4 f2 = ((const float4*)src)[2];
            float4 f3 = ((const float4*)src)[3];
            union { uint4 u; unsigned short s[8]; } p0, p1;
            p0.s[0] = f2b(f0.x); p0.s[1] = f2b(f0.y); p0.s[2] = f2b(f0.z); p0.s[3] = f2b(f0.w);
            p0.s[4] = f2b(f1.x); p0.s[5] = f2b(f1.y); p0.s[6] = f2b(f1.z); p0.s[7] = f2b(f1.w);
            p1.s[0] = f2b(f2.x); p1.s[1] = f2b(f2.y); p1.s[2] = f2b(f2.z); p1.s[3] = f2b(f2.w);
            p1.s[4] = f2b(f3.x); p1.s[5] = f2b(f3.y); p1.s[6] = f2b(f3.z); p1.s[7] = f2b(f3.w);
            *(uint4*)&As[ar][ac] = p0.u;
            *(uint4*)&As[ar][ac + 8] = p1.u;
        }
        __syncthreads();

        bf16x8 av[4], bv[4];
#pragma unroll
        for (int i = 0; i < 4; ++i)
            av[i] = *(const bf16x8*)&As[wm * 64 + 16 * i + l16][quad * 8];
#pragma unroll
        for (int i = 0; i < 4; ++i)
            bv[i] = *(const bf16x8*)&Ws[wn * 64 + 16 * i + l16][quad * 8];
#pragma unroll
        for (int i = 0; i < 4; ++i)
#pragma unroll
            for (int j = 0; j < 4; ++j)
                acc[i][j] = __builtin_amdgcn_mfma_f32_16x16x32_bf16(av[i], bv[j], acc[i][j], 0, 0, 0);
        __syncthreads();
    }

#pragma unroll
    for (int i = 0; i < 4; ++i)
#pragma unroll
        for (int j = 0; j < 4; ++j) {
            const int gn = n0 + wn * 64 + 16 * j + l16;
#pragma unroll
            for (int r = 0; r < 4; ++r) {
                const int gm = m0 + wm * 64 + 16 * i + quad * 4 + r;
                C[(size_t)gm * DM + gn] = f2b(acc[i][j][r]);
            }
        }
}

// ---------------------------------------------------------------------------
// Kernel 1b: bf16 GEMM (A bf16, Wt bf16 pre-transposed), both operands staged
// with global_load_lds width 16. Tile 128x128, BK=32. Epilogue: +bias, relu,
// +residual(bf16), output bf16 bits or fp32.
// ---------------------------------------------------------------------------
template <typename CT>
__global__ __launch_bounds__(256) void gemm_bf(const unsigned short* __restrict__ A,
                                               const unsigned short* __restrict__ Wt,
                                               CT* __restrict__ C,
                                               const float* __restrict__ bias,
                                               const unsigned short* __restrict__ res,
                                               int relu) {
    __shared__ __align__(16) unsigned short As[128][32];
    __shared__ __align__(16) unsigned short Ws[128][32];

    const int t = threadIdx.x;
    const int m0 = blockIdx.x * 128;
    const int n0 = blockIdx.y * 128;
    const int w = t >> 6, lane = t & 63;
    const int quad = lane >> 4, l16 = lane & 15;
    const int wm = w & 1, wn = w >> 1;
    const int srow = 16 * w + (lane >> 2);
    const int scol = 8 * (lane & 3);

    f32x4 acc[4][4];
#pragma unroll
    for (int i = 0; i < 4; ++i)
#pragma unroll
        for (int j = 0; j < 4; ++j) acc[i][j] = (f32x4){0.f, 0.f, 0.f, 0.f};

    for (int k0 = 0; k0 < DM; k0 += 32) {
#pragma unroll
        for (int j = 0; j < 2; ++j) {
            gld16(&A[(size_t)(m0 + srow + 64 * j) * DM + k0 + scol],
                  &As[16 * w + 64 * j][0]);
            gld16(&Wt[(size_t)(n0 + srow + 64 * j) * DM + k0 + scol],
                  &Ws[16 * w + 64 * j][0]);
        }
        __syncthreads();

        bf16x8 av[4], bv[4];
#pragma unroll
        for (int i = 0; i < 4; ++i)
            av[i] = *(const bf16x8*)&As[wm * 64 + 16 * i + l16][quad * 8];
#pragma unroll
        for (int i = 0; i < 4; ++i)
            bv[i] = *(const bf16x8*)&Ws[wn * 64 + 16 * i + l16][quad * 8];
#pragma unroll
        for (int i = 0; i < 4; ++i)
#pragma unroll
            for (int j = 0; j < 4; ++j)
                acc[i][j] = __builtin_amdgcn_mfma_f32_16x16x32_bf16(av[i], bv[j], acc[i][j], 0, 0, 0);
        __syncthreads();
    }

#pragma unroll
    for (int i = 0; i < 4; ++i)
#pragma unroll
        for (int j = 0; j < 4; ++j) {
            const int gn = n0 + wn * 64 + 16 * j + l16;
            const float badd = bias ? bias[gn] : 0.0f;
#pragma unroll
            for (int r = 0; r < 4; ++r) {
                const int gm = m0 + wm * 64 + 16 * i + quad * 4 + r;
                float cv = acc[i][j][r] + badd;
                if (relu) cv = fmaxf(cv, 0.0f);
                if (res) cv += b2f(res[(size_t)gm * DM + gn]);
                if constexpr (std::is_same<CT, float>::value) {
                    C[(size_t)gm * DM + gn] = cv;
                } else {
                    C[(size_t)gm * DM + gn] = f2b(cv);
                }
            }
        }
}

// ---------------------------------------------------------------------------
// Kernel 2: MFMA flash attention (unchanged from round 3 — passing, 112 µs)
// ---------------------------------------------------------------------------
__global__ __launch_bounds__(256) void attn_mfma(const unsigned short* Q,
                                                 const unsigned short* __restrict__ K,
                                                 const unsigned short* __restrict__ V,
                                                 unsigned short* O,
                                                 const int* __restrict__ lens) {
    __shared__ __align__(16) unsigned short Ks[64][72];      // [key][hd]
    __shared__ __align__(16) unsigned short Vt[64][72];      // [hd][key]
    __shared__ __align__(16) unsigned short Ps[4][16][72];   // per-wave [qrow][key]

    const int t = threadIdx.x;
    const int bid = blockIdx.x;                 // 16 * 12 * 8 = 1536
    const int q0 = (bid & 15) * 64;
    const int h = (bid >> 4) % NH;
    const int b = bid / (16 * NH);
    const int vl1 = lens[b];
    const int vl2 = lens[8 + b];
    const int wid = t >> 6;
    const int lane = t & 63;
    const int quad = lane >> 4;
    const int l16 = lane & 15;

    bf16x8 qa0, qa1;
    {
        const unsigned short* qp =
            &Q[(size_t)(b * SEQ + q0 + 16 * wid + l16) * DM + h * HD + quad * 8];
        qa0 = *(const bf16x8*)qp;
        qa1 = *(const bf16x8*)(qp + 32);
    }

    f32x4 o[4];
#pragma unroll
    for (int ct = 0; ct < 4; ++ct) o[ct] = (f32x4){0.f, 0.f, 0.f, 0.f};
    float m_i[4], l_i[4];
    bool qok[4];
#pragma unroll
    for (int r = 0; r < 4; ++r) {
        m_i[r] = -3.0e38f;
        l_i[r] = 0.0f;
        qok[r] = (q0 + 16 * wid + quad * 4 + r) < vl2;
    }

    const int kkr = t >> 3;
    const int khc = (t & 7) * 8;
    const int vkr = t & 31;
    const int vhc = t >> 5;

    for (int c0 = 0; c0 < SEQ; c0 += 64) {
        __syncthreads();
        {
            const unsigned short* kp = &K[(size_t)(b * SEQ + c0 + kkr) * DM + h * HD + khc];
            *(uint4*)&Ks[kkr][khc] = *(const uint4*)kp;
            *(uint4*)&Ks[kkr + 32][khc] = *(const uint4*)(kp + (size_t)32 * DM);
        }
#pragma unroll
        for (int it = 0; it < 2; ++it) {
            union { uint4 u; unsigned short s[8]; } vv;
            vv.u = *(const uint4*)&V[(size_t)(b * SEQ + c0 + vkr + 32 * it) * DM + h * HD + vhc * 8];
#pragma unroll
            for (int j = 0; j < 8; ++j) Vt[vhc * 8 + j][vkr + 32 * it] = vv.s[j];
        }
        __syncthreads();

        f32x4 s[4];
#pragma unroll
        for (int ct = 0; ct < 4; ++ct) {
            f32x4 acc = (f32x4){0.f, 0.f, 0.f, 0.f};
            bf16x8 b0v = *(const bf16x8*)&Ks[16 * ct + l16][quad * 8];
            bf16x8 b1v = *(const bf16x8*)&Ks[16 * ct + l16][32 + quad * 8];
            acc = __builtin_amdgcn_mfma_f32_16x16x32_bf16(qa0, b0v, acc, 0, 0, 0);
            acc = __builtin_amdgcn_mfma_f32_16x16x32_bf16(qa1, b1v, acc, 0, 0, 0);
            s[ct] = acc;
        }
#pragma unroll
        for (int ct = 0; ct < 4; ++ct) {
            const bool kok = (c0 + 16 * ct + l16) < vl1;
#pragma unroll
            for (int r = 0; r < 4; ++r) {
                s[ct][r] = (kok && qok[r]) ? s[ct][r] * 0.125f : -1.0e6f;
            }
        }
        float mx[4];
#pragma unroll
        for (int r = 0; r < 4; ++r)
            mx[r] = fmaxf(fmaxf(s[0][r], s[1][r]), fmaxf(s[2][r], s[3][r]));
#pragma unroll
        for (int d = 1; d < 16; d <<= 1) {
#pragma unroll
            for (int r = 0; r < 4; ++r) mx[r] = fmaxf(mx[r], __shfl_xor(mx[r], d, 64));
        }
        float alpha[4], sum[4];
#pragma unroll
        for (int r = 0; r < 4; ++r) {
            float mn = fmaxf(m_i[r], mx[r]);
            alpha[r] = __expf(m_i[r] - mn);
            m_i[r] = mn;
            sum[r] = 0.0f;
        }
#pragma unroll
        for (int ct = 0; ct < 4; ++ct) {
#pragma unroll
            for (int r = 0; r < 4; ++r) {
                float p = __expf(s[ct][r] - m_i[r]);
                s[ct][r] = p;
                sum[r] += p;
            }
        }
#pragma unroll
        for (int d = 1; d < 16; d <<= 1) {
#pragma unroll
            for (int r = 0; r < 4; ++r) sum[r] += __shfl_xor(sum[r], d, 64);
        }
#pragma unroll
        for (int r = 0; r < 4; ++r) l_i[r] = l_i[r] * alpha[r] + sum[r];
#pragma unroll
        for (int ct = 0; ct < 4; ++ct)
#pragma unroll
            for (int r = 0; r < 4; ++r) o[ct][r] *= alpha[r];
#pragma unroll
        for (int ct = 0; ct < 4; ++ct)
#pragma unroll
            for (int r = 0; r < 4; ++r)
                Ps[wid][quad * 4 + r][16 * ct + l16] = f2b(s[ct][r]);
        bf16x8 pa0 = *(const bf16x8*)&Ps[wid][l16][quad * 8];
        bf16x8 pa1 = *(const bf16x8*)&Ps[wid][l16][32 + quad * 8];
#pragma unroll
        for (int ct = 0; ct < 4; ++ct) {
            bf16x8 vb0 = *(const bf16x8*)&Vt[16 * ct + l16][quad * 8];
            bf16x8 vb1 = *(const bf16x8*)&Vt[16 * ct + l16][32 + quad * 8];
            o[ct] = __builtin_amdgcn_mfma_f32_16x16x32_bf16(pa0, vb0, o[ct], 0, 0, 0);
            o[ct] = __builtin_amdgcn_mfma_f32_16x16x32_bf16(pa1, vb1, o[ct], 0, 0, 0);
        }
    }

#pragma unroll
    for (int r = 0; r < 4; ++r) {
        float inv = 1.0f / l_i[r];
        const size_t row = (size_t)(b * SEQ + q0 + 16 * wid + quad * 4 + r);
#pragma unroll
        for (int ct = 0; ct < 4; ++ct) {
            O[row * DM + h * HD + 16 * ct + l16] = f2b(o[ct][r] * inv);
        }
    }
}

// ---------------------------------------------------------------------------
// Kernel 3: row LayerNorm over D=768, fp32 in/out, IN PLACE on d_out.
// ---------------------------------------------------------------------------
__global__ __launch_bounds__(256) void ln_kernel(float* __restrict__ X,
                                                 const float* __restrict__ g,
                                                 const float* __restrict__ bvec) {
    __shared__ float red[256];
    const int row = blockIdx.x;
    const int t = threadIdx.x;
    float* xr = X + (size_t)row * DM;
    float x0 = xr[t];
    float x1 = xr[t + 256];
    float x2 = xr[t + 512];
    red[t] = x0 + x1 + x2;
    __syncthreads();
    for (int off = 128; off > 0; off >>= 1) {
        if (t < off) red[t] += red[t + off];
        __syncthreads();
    }
    float mu = red[0] * (1.0f / 768.0f);
    __syncthreads();
    float d0 = x0 - mu, d1 = x1 - mu, d2 = x2 - mu;
    red[t] = d0 * d0 + d1 * d1 + d2 * d2;
    __syncthreads();
    for (int off = 128; off > 0; off >>= 1) {
        if (t < off) red[t] += red[t + off];
        __syncthreads();
    }
    float rstd = rsqrtf(red[0] * (1.0f / 768.0f) + 1e-5f);
    xr[t]       = d0 * rstd * g[t]       + bvec[t];
    xr[t + 256] = d1 * rstd * g[t + 256] + bvec[t + 256];
    xr[t + 512] = d2 * rstd * g[t + 512] + bvec[t + 512];
}

// ---------------------------------------------------------------------------
extern "C" void kernel_launch(void* const* d_in, const int* in_sizes, int n_in,
                              void* d_out, int out_size, void* d_ws, size_t ws_size,
                              hipStream_t stream) {
    const float* queries = (const float*)d_in[0];
    const float* keys    = (const float*)d_in[1];
    const float* values  = (const float*)d_in[2];
    const int* mask1 = (const int*)d_in[3];
    const int* mask2 = (const int*)d_in[4];
    const float* Wq  = (const float*)d_in[5];
    const float* Wk  = (const float*)d_in[6];
    const float* Wv  = (const float*)d_in[7];
    const float* Wo  = (const float*)d_in[8];
    const float* d1w = (const float*)d_in[9];
    const float* d1b = (const float*)d_in[10];
    const float* d2w = (const float*)d_in[11];
    const float* d2b = (const float*)d_in[12];
    const float* lng = (const float*)d_in[13];
    const float* lnb = (const float*)d_in[14];

    // workspace: [lens 256B][b0][b1][b2][Wt x6]   (44.8 MB total)
    char* ws = (char*)d_ws;
    int* lens = (int*)ws;
    const size_t NB = (size_t)NROWS * DM * sizeof(unsigned short);   // 12.58 MB
    unsigned short* b0 = (unsigned short*)(ws + 256);
    unsigned short* b1 = (unsigned short*)(ws + 256 + NB);
    unsigned short* b2 = (unsigned short*)(ws + 256 + 2 * NB);
    unsigned short* wt = (unsigned short*)(ws + 256 + 3 * NB);       // 6 x 768*768
    float* xout = (float*)d_out;

    lens_kernel<<<16, 256, 0, stream>>>(mask1, mask2, lens);
    cvt_wt<<<dim3(24, 24, 6), 256, 0, stream>>>(Wq, Wk, Wv, Wo, d1w, d2w, wt);

    // grouped QKV projection: 64 x (3 groups * 6 n-tiles)
    qkv_gemm<<<dim3(64, 18), 256, 0, stream>>>(queries, keys, values, wt, b0, b1, b2);

    attn_mfma<<<16 * NH * BATCH, 256, 0, stream>>>(b0, b1, b2, b0, lens);  // O in place over Q

    const size_t WT = (size_t)DM * DM;
    gemm_bf<unsigned short><<<dim3(64, 6), 256, 0, stream>>>(b0, wt + 3 * WT, b1, nullptr, nullptr, 0); // mha
    gemm_bf<unsigned short><<<dim3(64, 6), 256, 0, stream>>>(b1, wt + 4 * WT, b2, d1b, nullptr, 1);     // ffn hidden
    gemm_bf<float><<<dim3(64, 6), 256, 0, stream>>>(b2, wt + 5 * WT, xout, d2b, b1, 0);                 // x -> d_out

    ln_kernel<<<NROWS, 256, 0, stream>>>(xout, lng, lnb);  // in place
}

// Round 5
// 361.398 us; speedup vs baseline: 3.0506x; 1.1056x over previous
//
#include <hip/hip_runtime.h>
#include <hip/hip_bf16.h>
#include <type_traits>

// Problem constants (fixed by the reference)
#define DM   768
#define NH   12
#define HD   64
#define BATCH 8
#define SEQ  1024
#define NROWS (BATCH * SEQ)   // 8192

typedef short bf16x8 __attribute__((ext_vector_type(8)));
typedef float f32x4 __attribute__((ext_vector_type(4)));

// fp32 -> bf16 bits, round-to-nearest-even (no libcall)
__device__ inline unsigned short f2b(float x) {
    union { float f; unsigned int u; } v; v.f = x;
    unsigned int r = v.u + 0x7FFFu + ((v.u >> 16) & 1u);
    return (unsigned short)(r >> 16);
}
// bf16 bits -> fp32
__device__ inline float b2f(unsigned short u) {
    union { float f; unsigned int x; } v; v.x = ((unsigned int)u) << 16;
    return v.f;
}

// async global->LDS, 16 B per lane; LDS dest = wave-uniform base + lane*16
__device__ inline void gld16(const unsigned short* g, unsigned short* l) {
    __builtin_amdgcn_global_load_lds(
        (const __attribute__((address_space(1))) unsigned int*)g,
        (__attribute__((address_space(3))) unsigned int*)l, 16, 0, 0);
}

// ---------------------------------------------------------------------------
// Kernel 0: per-batch valid lengths from binary masks (int32).
// ---------------------------------------------------------------------------
__global__ __launch_bounds__(256) void lens_kernel(const int* __restrict__ m1,
                                                   const int* __restrict__ m2,
                                                   int* __restrict__ lens) {
    __shared__ int red[256];
    const int bid = blockIdx.x;           // 0..15
    const int b = bid & 7;
    const int* m = (bid < 8) ? m1 : m2;
    const int t = threadIdx.x;
    int cnt = 0;
    for (int i = t; i < SEQ; i += 256) cnt += (m[b * SEQ + i] != 0) ? 1 : 0;
    red[t] = cnt;
    __syncthreads();
    for (int off = 128; off > 0; off >>= 1) {
        if (t < off) red[t] += red[t + off];
        __syncthreads();
    }
    if (t == 0) lens[bid] = red[0];
}

// ---------------------------------------------------------------------------
// Kernel 0b: convert+transpose the 6 weight matrices.
// W[k][n] fp32  ->  Wt[n][k] bf16 bits   (z = which weight)
// ---------------------------------------------------------------------------
__global__ __launch_bounds__(256) void cvt_wt(const float* __restrict__ w0,
                                              const float* __restrict__ w1,
                                              const float* __restrict__ w2,
                                              const float* __restrict__ w3,
                                              const float* __restrict__ w4,
                                              const float* __restrict__ w5,
                                              unsigned short* __restrict__ wt) {
    __shared__ float tile[32][33];
    const int z = blockIdx.z;
    const float* W = (z == 0) ? w0 : (z == 1) ? w1 : (z == 2) ? w2
                   : (z == 3) ? w3 : (z == 4) ? w4 : w5;
    unsigned short* Wt = wt + (size_t)z * DM * DM;
    const int n0 = blockIdx.x * 32;
    const int k0 = blockIdx.y * 32;
    const int tx = threadIdx.x & 31;
    const int ty = threadIdx.x >> 5;  // 0..7
#pragma unroll
    for (int r = 0; r < 4; ++r)
        tile[ty + 8 * r][tx] = W[(size_t)(k0 + ty + 8 * r) * DM + n0 + tx];
    __syncthreads();
#pragma unroll
    for (int r = 0; r < 4; ++r)
        Wt[(size_t)(n0 + ty + 8 * r) * DM + k0 + tx] = f2b(tile[tx][ty + 8 * r]);
}

// ---------------------------------------------------------------------------
// Kernel 1a: grouped QKV GEMM (unchanged from round 4 — passing).
// ---------------------------------------------------------------------------
__global__ __launch_bounds__(256) void qkv_gemm(const float* __restrict__ a0,
                                                const float* __restrict__ a1,
                                                const float* __restrict__ a2,
                                                const unsigned short* __restrict__ wt,
                                                unsigned short* __restrict__ c0,
                                                unsigned short* __restrict__ c1,
                                                unsigned short* __restrict__ c2) {
    __shared__ __align__(16) unsigned short As[128][32];
    __shared__ __align__(16) unsigned short Ws[128][32];

    const int t = threadIdx.x;
    const int g = blockIdx.y / 6;
    const int m0 = blockIdx.x * 128;
    const int n0 = (blockIdx.y % 6) * 128;
    const float* A = (g == 0) ? a0 : (g == 1) ? a1 : a2;
    const unsigned short* Wt = wt + (size_t)g * DM * DM;
    unsigned short* C = (g == 0) ? c0 : (g == 1) ? c1 : c2;

    const int w = t >> 6, lane = t & 63;
    const int quad = lane >> 4, l16 = lane & 15;
    const int wm = w & 1, wn = w >> 1;
    const int srow = 16 * w + (lane >> 2);
    const int scol = 8 * (lane & 3);
    const int ar = t >> 1;
    const int ac = (t & 1) * 16;

    f32x4 acc[4][4];
#pragma unroll
    for (int i = 0; i < 4; ++i)
#pragma unroll
        for (int j = 0; j < 4; ++j) acc[i][j] = (f32x4){0.f, 0.f, 0.f, 0.f};

    for (int k0 = 0; k0 < DM; k0 += 32) {
#pragma unroll
        for (int j = 0; j < 2; ++j)
            gld16(&Wt[(size_t)(n0 + srow + 64 * j) * DM + k0 + scol],
                  &Ws[16 * w + 64 * j][0]);
        {
            const float* src = &A[(size_t)(m0 + ar) * DM + k0 + ac];
            float4 f0 = ((const float4*)src)[0];
            float4 f1 = ((const float4*)src)[1];
            float4 f2 = ((const float4*)src)[2];
            float4 f3 = ((const float4*)src)[3];
            union { uint4 u; unsigned short s[8]; } p0, p1;
            p0.s[0] = f2b(f0.x); p0.s[1] = f2b(f0.y); p0.s[2] = f2b(f0.z); p0.s[3] = f2b(f0.w);
            p0.s[4] = f2b(f1.x); p0.s[5] = f2b(f1.y); p0.s[6] = f2b(f1.z); p0.s[7] = f2b(f1.w);
            p1.s[0] = f2b(f2.x); p1.s[1] = f2b(f2.y); p1.s[2] = f2b(f2.z); p1.s[3] = f2b(f2.w);
            p1.s[4] = f2b(f3.x); p1.s[5] = f2b(f3.y); p1.s[6] = f2b(f3.z); p1.s[7] = f2b(f3.w);
            *(uint4*)&As[ar][ac] = p0.u;
            *(uint4*)&As[ar][ac + 8] = p1.u;
        }
        __syncthreads();

        bf16x8 av[4], bv[4];
#pragma unroll
        for (int i = 0; i < 4; ++i)
            av[i] = *(const bf16x8*)&As[wm * 64 + 16 * i + l16][quad * 8];
#pragma unroll
        for (int i = 0; i < 4; ++i)
            bv[i] = *(const bf16x8*)&Ws[wn * 64 + 16 * i + l16][quad * 8];
#pragma unroll
        for (int i = 0; i < 4; ++i)
#pragma unroll
            for (int j = 0; j < 4; ++j)
                acc[i][j] = __builtin_amdgcn_mfma_f32_16x16x32_bf16(av[i], bv[j], acc[i][j], 0, 0, 0);
        __syncthreads();
    }

#pragma unroll
    for (int i = 0; i < 4; ++i)
#pragma unroll
        for (int j = 0; j < 4; ++j) {
            const int gn = n0 + wn * 64 + 16 * j + l16;
#pragma unroll
            for (int r = 0; r < 4; ++r) {
                const int gm = m0 + wm * 64 + 16 * i + quad * 4 + r;
                C[(size_t)gm * DM + gn] = f2b(acc[i][j][r]);
            }
        }
}

// ---------------------------------------------------------------------------
// Kernel 1b: bf16 GEMM 128x128 (unchanged from round 4 — passing).
// ---------------------------------------------------------------------------
template <typename CT>
__global__ __launch_bounds__(256) void gemm_bf(const unsigned short* __restrict__ A,
                                               const unsigned short* __restrict__ Wt,
                                               CT* __restrict__ C,
                                               const float* __restrict__ bias,
                                               const unsigned short* __restrict__ res,
                                               int relu) {
    __shared__ __align__(16) unsigned short As[128][32];
    __shared__ __align__(16) unsigned short Ws[128][32];

    const int t = threadIdx.x;
    const int m0 = blockIdx.x * 128;
    const int n0 = blockIdx.y * 128;
    const int w = t >> 6, lane = t & 63;
    const int quad = lane >> 4, l16 = lane & 15;
    const int wm = w & 1, wn = w >> 1;
    const int srow = 16 * w + (lane >> 2);
    const int scol = 8 * (lane & 3);

    f32x4 acc[4][4];
#pragma unroll
    for (int i = 0; i < 4; ++i)
#pragma unroll
        for (int j = 0; j < 4; ++j) acc[i][j] = (f32x4){0.f, 0.f, 0.f, 0.f};

    for (int k0 = 0; k0 < DM; k0 += 32) {
#pragma unroll
        for (int j = 0; j < 2; ++j) {
            gld16(&A[(size_t)(m0 + srow + 64 * j) * DM + k0 + scol],
                  &As[16 * w + 64 * j][0]);
            gld16(&Wt[(size_t)(n0 + srow + 64 * j) * DM + k0 + scol],
                  &Ws[16 * w + 64 * j][0]);
        }
        __syncthreads();

        bf16x8 av[4], bv[4];
#pragma unroll
        for (int i = 0; i < 4; ++i)
            av[i] = *(const bf16x8*)&As[wm * 64 + 16 * i + l16][quad * 8];
#pragma unroll
        for (int i = 0; i < 4; ++i)
            bv[i] = *(const bf16x8*)&Ws[wn * 64 + 16 * i + l16][quad * 8];
#pragma unroll
        for (int i = 0; i < 4; ++i)
#pragma unroll
            for (int j = 0; j < 4; ++j)
                acc[i][j] = __builtin_amdgcn_mfma_f32_16x16x32_bf16(av[i], bv[j], acc[i][j], 0, 0, 0);
        __syncthreads();
    }

#pragma unroll
    for (int i = 0; i < 4; ++i)
#pragma unroll
        for (int j = 0; j < 4; ++j) {
            const int gn = n0 + wn * 64 + 16 * j + l16;
            const float badd = bias ? bias[gn] : 0.0f;
#pragma unroll
            for (int r = 0; r < 4; ++r) {
                const int gm = m0 + wm * 64 + 16 * i + quad * 4 + r;
                float cv = acc[i][j][r] + badd;
                if (relu) cv = fmaxf(cv, 0.0f);
                if (res) cv += b2f(res[(size_t)gm * DM + gn]);
                if constexpr (std::is_same<CT, float>::value) {
                    C[(size_t)gm * DM + gn] = cv;
                } else {
                    C[(size_t)gm * DM + gn] = f2b(cv);
                }
            }
        }
}

// ---------------------------------------------------------------------------
// Kernel 2: MFMA flash attention, round-5 rework.
//  - Software pipeline: K/V tile t+1 loaded into VGPRs during tile t compute.
//  - Vt staging: row-uniform scalar stores (row = wid*16+j per instruction,
//    col = lane) -> perfect 2-way bank access (free).
//  - Ps stores XOR-swizzled on 16B groups: store group g^(row>>2); A-frag
//    reads unswizzle with quad^(l16>>2). Conflict-free stores.
//  - No-rescale softmax: scores are bounded, so p = exp(s*0.125) without
//    max-subtraction is exact vs reference (shift-invariant; masked cols
//    underflow to 0 both ways). Fully-masked rows (q >= vl2 or vl1==0):
//    p = 1 for all 1024 keys -> l = 1024 -> uniform softmax = reference.
//    l accumulates per-lane; one shfl reduce at the end.
// O written in place over Q (regions disjoint per block; Q read only at start).
// ---------------------------------------------------------------------------
__global__ __launch_bounds__(256) void attn_mfma(const unsigned short* Q,
                                                 const unsigned short* __restrict__ K,
                                                 const unsigned short* __restrict__ V,
                                                 unsigned short* O,
                                                 const int* __restrict__ lens) {
    __shared__ __align__(16) unsigned short Ks[64][72];      // [key][hd]
    __shared__ __align__(16) unsigned short Vt[64][72];      // [hd][key]
    __shared__ __align__(16) unsigned short Ps[4][16][72];   // per-wave [qrow][key], swizzled

    const int t = threadIdx.x;
    const int bid = blockIdx.x;                 // 16 * 12 * 8 = 1536
    const int q0 = (bid & 15) * 64;
    const int h = (bid >> 4) % NH;
    const int b = bid / (16 * NH);
    const int vl1 = lens[b];                    // key-axis valid length
    const int vl2 = lens[8 + b];                // query-axis valid length
    const int wid = t >> 6;
    const int lane = t & 63;
    const int quad = lane >> 4;
    const int l16 = lane & 15;

    // Q fragments (A-operand): rows q0+16*wid+l16, k = hd
    bf16x8 qa0, qa1;
    {
        const unsigned short* qp =
            &Q[(size_t)(b * SEQ + q0 + 16 * wid + l16) * DM + h * HD + quad * 8];
        qa0 = *(const bf16x8*)qp;
        qa1 = *(const bf16x8*)(qp + 32);
    }

    f32x4 o[4];
#pragma unroll
    for (int ct = 0; ct < 4; ++ct) o[ct] = (f32x4){0.f, 0.f, 0.f, 0.f};
    float suml[4];
    bool rbad[4];
#pragma unroll
    for (int r = 0; r < 4; ++r) {
        suml[r] = 0.0f;
        rbad[r] = ((q0 + 16 * wid + quad * 4 + r) >= vl2) || (vl1 == 0);
    }

    // staging assignments
    const int kkr = t >> 3;            // K: key row 0..31 (and +32)
    const int khc = (t & 7) * 8;       // K: hd offset
    const unsigned short* kbase = &K[(size_t)(b * SEQ) * DM + h * HD];
    const unsigned short* vbase = &V[(size_t)(b * SEQ) * DM + h * HD];

    // preload tile 0 into registers
    uint4 kr0 = *(const uint4*)&kbase[(size_t)kkr * DM + khc];
    uint4 kr1 = *(const uint4*)&kbase[(size_t)(kkr + 32) * DM + khc];
    uint4 vr0 = *(const uint4*)&vbase[(size_t)lane * DM + wid * 16];
    uint4 vr1 = *(const uint4*)&vbase[(size_t)lane * DM + wid * 16 + 8];

    const int k2 = l16 >> 2;  // Ps read unswizzle key

    for (int tile = 0; tile < 16; ++tile) {
        const int c0 = tile * 64;
        // write staged registers -> LDS
        *(uint4*)&Ks[kkr][khc] = kr0;
        *(uint4*)&Ks[kkr + 32][khc] = kr1;
        {
            union { uint4 u; unsigned short s[8]; } va, vb;
            va.u = vr0; vb.u = vr1;
#pragma unroll
            for (int j = 0; j < 8; ++j) Vt[wid * 16 + j][lane] = va.s[j];
#pragma unroll
            for (int j = 0; j < 8; ++j) Vt[wid * 16 + 8 + j][lane] = vb.s[j];
        }
        __syncthreads();

        // prefetch next tile (latency hidden behind this tile's compute)
        if (tile < 15) {
            const int c1 = c0 + 64;
            kr0 = *(const uint4*)&kbase[(size_t)(c1 + kkr) * DM + khc];
            kr1 = *(const uint4*)&kbase[(size_t)(c1 + kkr + 32) * DM + khc];
            vr0 = *(const uint4*)&vbase[(size_t)(c1 + lane) * DM + wid * 16];
            vr1 = *(const uint4*)&vbase[(size_t)(c1 + lane) * DM + wid * 16 + 8];
        }

        // S = Q K^T  (C layout: reg r = row quad*4+r, col = 16ct+l16)
        f32x4 s[4];
#pragma unroll
        for (int ct = 0; ct < 4; ++ct) {
            f32x4 acc = (f32x4){0.f, 0.f, 0.f, 0.f};
            bf16x8 b0v = *(const bf16x8*)&Ks[16 * ct + l16][quad * 8];
            bf16x8 b1v = *(const bf16x8*)&Ks[16 * ct + l16][32 + quad * 8];
            acc = __builtin_amdgcn_mfma_f32_16x16x32_bf16(qa0, b0v, acc, 0, 0, 0);
            acc = __builtin_amdgcn_mfma_f32_16x16x32_bf16(qa1, b1v, acc, 0, 0, 0);
            s[ct] = acc;
        }
        // p = exp(s/8) with masking; accumulate row sums per lane
#pragma unroll
        for (int ct = 0; ct < 4; ++ct) {
            const bool kok = (c0 + 16 * ct + l16) < vl1;
#pragma unroll
            for (int r = 0; r < 4; ++r) {
                float e = __expf(s[ct][r] * 0.125f);
                float p = kok ? e : 0.0f;
                p = rbad[r] ? 1.0f : p;
                s[ct][r] = p;
                suml[r] += p;
            }
        }
        // P -> per-wave LDS (C layout -> A layout), XOR-swizzled 16B groups
#pragma unroll
        for (int ct = 0; ct < 4; ++ct) {
            const int g = 2 * ct + (l16 >> 3);
            const int c = l16 & 7;
            const int gs = (g ^ quad) * 8 + c;
#pragma unroll
            for (int r = 0; r < 4; ++r)
                Ps[wid][quad * 4 + r][gs] = f2b(s[ct][r]);
        }
        bf16x8 pa0 = *(const bf16x8*)&Ps[wid][l16][(quad ^ k2) * 8];
        bf16x8 pa1 = *(const bf16x8*)&Ps[wid][l16][((4 + quad) ^ k2) * 8];
        // O += P V
#pragma unroll
        for (int ct = 0; ct < 4; ++ct) {
            bf16x8 vb0 = *(const bf16x8*)&Vt[16 * ct + l16][quad * 8];
            bf16x8 vb1 = *(const bf16x8*)&Vt[16 * ct + l16][32 + quad * 8];
            o[ct] = __builtin_amdgcn_mfma_f32_16x16x32_bf16(pa0, vb0, o[ct], 0, 0, 0);
            o[ct] = __builtin_amdgcn_mfma_f32_16x16x32_bf16(pa1, vb1, o[ct], 0, 0, 0);
        }
        __syncthreads();  // all reads of Ks/Vt done before next tile's writes
    }

    // epilogue: reduce l across the 16 lanes of each row group, O /= l
#pragma unroll
    for (int d = 1; d < 16; d <<= 1) {
#pragma unroll
        for (int r = 0; r < 4; ++r) suml[r] += __shfl_xor(suml[r], d, 64);
    }
#pragma unroll
    for (int r = 0; r < 4; ++r) {
        float inv = 1.0f / suml[r];
        const size_t row = (size_t)(b * SEQ + q0 + 16 * wid + quad * 4 + r);
#pragma unroll
        for (int ct = 0; ct < 4; ++ct) {
            O[row * DM + h * HD + 16 * ct + l16] = f2b(o[ct][r] * inv);
        }
    }
}

// ---------------------------------------------------------------------------
// Kernel 3: row LayerNorm over D=768, fp32 in/out, IN PLACE on d_out.
// ---------------------------------------------------------------------------
__global__ __launch_bounds__(256) void ln_kernel(float* __restrict__ X,
                                                 const float* __restrict__ g,
                                                 const float* __restrict__ bvec) {
    __shared__ float red[256];
    const int row = blockIdx.x;
    const int t = threadIdx.x;
    float* xr = X + (size_t)row * DM;
    float x0 = xr[t];
    float x1 = xr[t + 256];
    float x2 = xr[t + 512];
    red[t] = x0 + x1 + x2;
    __syncthreads();
    for (int off = 128; off > 0; off >>= 1) {
        if (t < off) red[t] += red[t + off];
        __syncthreads();
    }
    float mu = red[0] * (1.0f / 768.0f);
    __syncthreads();
    float d0 = x0 - mu, d1 = x1 - mu, d2 = x2 - mu;
    red[t] = d0 * d0 + d1 * d1 + d2 * d2;
    __syncthreads();
    for (int off = 128; off > 0; off >>= 1) {
        if (t < off) red[t] += red[t + off];
        __syncthreads();
    }
    float rstd = rsqrtf(red[0] * (1.0f / 768.0f) + 1e-5f);
    xr[t]       = d0 * rstd * g[t]       + bvec[t];
    xr[t + 256] = d1 * rstd * g[t + 256] + bvec[t + 256];
    xr[t + 512] = d2 * rstd * g[t + 512] + bvec[t + 512];
}

// ---------------------------------------------------------------------------
extern "C" void kernel_launch(void* const* d_in, const int* in_sizes, int n_in,
                              void* d_out, int out_size, void* d_ws, size_t ws_size,
                              hipStream_t stream) {
    const float* queries = (const float*)d_in[0];
    const float* keys    = (const float*)d_in[1];
    const float* values  = (const float*)d_in[2];
    const int* mask1 = (const int*)d_in[3];
    const int* mask2 = (const int*)d_in[4];
    const float* Wq  = (const float*)d_in[5];
    const float* Wk  = (const float*)d_in[6];
    const float* Wv  = (const float*)d_in[7];
    const float* Wo  = (const float*)d_in[8];
    const float* d1w = (const float*)d_in[9];
    const float* d1b = (const float*)d_in[10];
    const float* d2w = (const float*)d_in[11];
    const float* d2b = (const float*)d_in[12];
    const float* lng = (const float*)d_in[13];
    const float* lnb = (const float*)d_in[14];

    // workspace: [lens 256B][b0][b1][b2][Wt x6]   (44.8 MB total)
    char* ws = (char*)d_ws;
    int* lens = (int*)ws;
    const size_t NB = (size_t)NROWS * DM * sizeof(unsigned short);   // 12.58 MB
    unsigned short* b0 = (unsigned short*)(ws + 256);
    unsigned short* b1 = (unsigned short*)(ws + 256 + NB);
    unsigned short* b2 = (unsigned short*)(ws + 256 + 2 * NB);
    unsigned short* wt = (unsigned short*)(ws + 256 + 3 * NB);       // 6 x 768*768
    float* xout = (float*)d_out;

    lens_kernel<<<16, 256, 0, stream>>>(mask1, mask2, lens);
    cvt_wt<<<dim3(24, 24, 6), 256, 0, stream>>>(Wq, Wk, Wv, Wo, d1w, d2w, wt);

    // grouped QKV projection: 64 x (3 groups * 6 n-tiles)
    qkv_gemm<<<dim3(64, 18), 256, 0, stream>>>(queries, keys, values, wt, b0, b1, b2);

    attn_mfma<<<16 * NH * BATCH, 256, 0, stream>>>(b0, b1, b2, b0, lens);  // O in place over Q

    const size_t WT = (size_t)DM * DM;
    gemm_bf<unsigned short><<<dim3(64, 6), 256, 0, stream>>>(b0, wt + 3 * WT, b1, nullptr, nullptr, 0); // mha
    gemm_bf<unsigned short><<<dim3(64, 6), 256, 0, stream>>>(b1, wt + 4 * WT, b2, d1b, nullptr, 1);     // ffn hidden
    gemm_bf<float><<<dim3(64, 6), 256, 0, stream>>>(b2, wt + 5 * WT, xout, d2b, b1, 0);                 // x -> d_out

    ln_kernel<<<NROWS, 256, 0, stream>>>(xout, lng, lnb);  // in place
}